// Round 2
// baseline (4404.255 us; speedup 1.0000x reference)
//
#include <hip/hip_runtime.h>

// LSTM: VOCAB=50000, EMBED=50, NFEAT=3, T=120, HIDDEN=300, NCLASS=5, BATCH=1024
// 160 blocks (16 batch-groups x 10 hidden-slices), 1 block/CU, normal launch.
// Wh'/Wx' (gate-permuted, padded, bf16, linear k-packed) persist in VGPRs for
// all 120 steps. h exchanged via ping-pong global buffer + per-(t,bg) flag
// counters with agent-scope release/acquire. Embedding gather done in-kernel
// (double-buffered x_lds, loads issued before the step's MFMAs).

#define BATCH 1024
#define TT    120
#define HID   300
#define KX    160   // padded K for x (150 -> 160)
#define KH    320   // padded K for h (300 -> 320)
#define NCOL  1280  // padded gate columns: 10 slices * 128
#define GH    10    // hidden slices
#define GB    16    // batch groups
#define BS    64    // batch rows per group
#define HSL   30    // hidden units per slice
#define HST   328   // h_lds row stride in shorts (656B = 41*16B -> 2-way alias, free)
#define XST   168   // x_lds row stride in shorts (336B = 21*16B)

typedef __attribute__((ext_vector_type(8))) short bf16x8;
typedef __attribute__((ext_vector_type(4))) float f32x4;

__device__ __forceinline__ unsigned short f2b(float f) {
  union { float f; unsigned u; } v; v.f = f;
  unsigned r = v.u + 0x7fffu + ((v.u >> 16) & 1u);
  return (unsigned short)(r >> 16);
}
__device__ __forceinline__ float sigm(float x) {
  return __builtin_amdgcn_rcpf(1.f + __expf(-x));
}
__device__ __forceinline__ float tanhf_(float x) {
  return 2.f * __builtin_amdgcn_rcpf(1.f + __expf(-2.f * x)) - 1.f;
}

// W[k][g*300 + j*30 + u0] -> Wp[((k>>3)*NCOL + c)*8 + (k&7)], c = j*128+g*32+u0
__global__ void k_reorder_w(const float* __restrict__ W, unsigned short* __restrict__ Wp,
                            int krows, int kpad) {
  int tid = blockIdx.x * 256 + threadIdx.x;
  if (tid >= kpad * NCOL) return;
  int c = tid % NCOL, k = tid / NCOL;
  int j = c >> 7, r = c & 127, g = r >> 5, u0 = r & 31;
  float val = 0.f;
  if (k < krows && u0 < HSL) val = W[k * 1200 + g * 300 + j * HSL + u0];
  Wp[((k >> 3) * NCOL + c) * 8 + (k & 7)] = f2b(val);
}

__global__ void k_reorder_b(const float* __restrict__ b, float* __restrict__ bp) {
  int c = blockIdx.x * 256 + threadIdx.x;
  if (c >= NCOL) return;
  int j = c >> 7, r = c & 127, g = r >> 5, u0 = r & 31;
  bp[c] = (u0 < HSL) ? b[g * 300 + j * HSL + u0] : 0.f;
}

// U[k][n] (300x5) -> Up[((k>>3)*16 + n)*8 + (k&7)], n padded to 16, k to 320
__global__ void k_reorder_u(const float* __restrict__ U, unsigned short* __restrict__ Up) {
  int tid = blockIdx.x * 256 + threadIdx.x;
  if (tid >= KH * 16) return;
  int n = tid % 16, k = tid / 16;
  float v = (k < HID && n < 5) ? U[k * 5 + n] : 0.f;
  Up[((k >> 3) * 16 + n) * 8 + (k & 7)] = f2b(v);
}

__launch_bounds__(256, 1)
__global__ void k_lstm(const int* __restrict__ ids, const float* __restrict__ embed,
                       const unsigned short* __restrict__ Wp,
                       const unsigned short* __restrict__ Wxp,
                       const float* __restrict__ bp,
                       const unsigned short* __restrict__ Up,
                       unsigned short* __restrict__ hbuf,   // [2][1024][320] bf16
                       int* __restrict__ flags,             // [120][16]
                       const float* __restrict__ b2,
                       float* __restrict__ out) {
  __shared__ __align__(16) unsigned short h_lds[BS * HST];
  __shared__ __align__(16) unsigned short x_lds[2][BS * XST];

  const int tid = threadIdx.x;
  const int bid = blockIdx.x;
  const int bg = bid / GH, j = bid % GH;
  const int lane = tid & 63, w = tid >> 6;
  const int wm = w >> 1, wu = w & 1;   // 4 waves: 2 M-halves x 2 unit-halves
  const int l15 = lane & 15, l4 = lane >> 4;

  // zero x_lds pads [150,168) once (uninitialized LDS could hold NaN bits)
  if (tid < BS) {
#pragma unroll
    for (int bq = 0; bq < 2; ++bq)
      for (int e = 150; e < XST; ++e) x_lds[bq][tid * XST + e] = 0;
  }

  const int colb = j * 128 + wu * 16 + l15;

  // persistent B fragments, linear k-pack: elem e of row (kk*4+l4) is k=kk*32+l4*8+e
  bf16x8 bh[10][4], bx[5][4];
#pragma unroll
  for (int kk = 0; kk < 10; ++kk)
#pragma unroll
    for (int g = 0; g < 4; ++g)
      bh[kk][g] = *(const bf16x8*)(Wp + ((kk * 4 + l4) * NCOL + colb + g * 32) * 8);
#pragma unroll
  for (int kk = 0; kk < 5; ++kk)
#pragma unroll
    for (int g = 0; g < 4; ++g)
      bx[kk][g] = *(const bf16x8*)(Wxp + ((kk * 4 + l4) * NCOL + colb + g * 32) * 8);

  float bias[4];
#pragma unroll
  for (int g = 0; g < 4; ++g) bias[g] = bp[colb + g * 32];
  const float b2v = (l15 < 5) ? b2[l15] : 0.f;

  const int u_local = wu * 16 + l15;
  const bool uvalid = (u_local < HSL);

  // gather x(0)
  if (tid < 192) {
    int xrow = tid / 3, xf = tid - 3 * xrow;
    int id = ids[((bg * BS + xrow) * TT + 0) * 3 + xf];
    const float* src = embed + (long)id * 50;
    unsigned short* dst = &x_lds[0][xrow * XST + xf * 50];
#pragma unroll
    for (int e = 0; e < 25; ++e) {
      float2 v = *(const float2*)(src + 2 * e);
      *(unsigned*)(dst + 2 * e) = (unsigned)f2b(v.x) | ((unsigned)f2b(v.y) << 16);
    }
  }
  __syncthreads();

  f32x4 acc[4][2];
  float cst[2][4];
#pragma unroll
  for (int g = 0; g < 4; ++g)
#pragma unroll
    for (int mt = 0; mt < 2; ++mt) acc[g][mt] = {0.f, 0.f, 0.f, 0.f};
#pragma unroll
  for (int mt = 0; mt < 2; ++mt)
#pragma unroll
    for (int r = 0; r < 4; ++r) cst[mt][r] = 0.f;

  for (int t = 0; t < TT; ++t) {
    if (t > 0) {
      if (tid == 0) {
        int* fp = flags + (t - 1) * GB + bg;
        int it = 0;
        while (__hip_atomic_load(fp, __ATOMIC_ACQUIRE, __HIP_MEMORY_SCOPE_AGENT) < GH) {
          __builtin_amdgcn_s_sleep(2);
          if (++it > 100000) break;  // bail -> wrong answer, not a hang
        }
      }
      __syncthreads();
      // stage h(t-1): linear 16B chunks (coalesced global, ~conflict-free LDS)
      const unsigned short* hsrc = hbuf + ((t - 1) & 1) * (BATCH * KH) + bg * BS * KH;
#pragma unroll
      for (int p = 0; p < 10; ++p) {
        int g = tid + 256 * p;          // 2560 chunks of 16B, 40 per row
        int row = g / 40, c = g - row * 40;
        *(int4*)(h_lds + row * HST + c * 8) = *(const int4*)(hsrc + g * 8);
      }
      __syncthreads();
    }

    // issue x(t+1) gather loads early; pack after the MFMAs
    float2 xv[25];
    int xrow = 0, xf = 0;
    const bool xact = (t + 1 < TT) && (tid < 192);
    if (xact) {
      xrow = tid / 3; xf = tid - 3 * xrow;
      int id = ids[((bg * BS + xrow) * TT + (t + 1)) * 3 + xf];
      const float* src = embed + (long)id * 50;
#pragma unroll
      for (int e = 0; e < 25; ++e) xv[e] = *(const float2*)(src + 2 * e);
    }

    // GEMM1: x_t @ Wx'
    {
      const unsigned short* xb = &x_lds[t & 1][(wm * 32 + l15) * XST + l4 * 8];
#pragma unroll
      for (int kk = 0; kk < 5; ++kk) {
        bf16x8 a0 = *(const bf16x8*)(xb + kk * 32);
        bf16x8 a1 = *(const bf16x8*)(xb + 16 * XST + kk * 32);
#pragma unroll
        for (int g = 0; g < 4; ++g) {
          acc[g][0] = __builtin_amdgcn_mfma_f32_16x16x32_bf16(a0, bx[kk][g], acc[g][0], 0, 0, 0);
          acc[g][1] = __builtin_amdgcn_mfma_f32_16x16x32_bf16(a1, bx[kk][g], acc[g][1], 0, 0, 0);
        }
      }
    }
    // GEMM2: h(t-1) @ Wh'
    if (t > 0) {
      const unsigned short* hb = h_lds + (wm * 32 + l15) * HST + l4 * 8;
#pragma unroll
      for (int kk = 0; kk < 10; ++kk) {
        bf16x8 a0 = *(const bf16x8*)(hb + kk * 32);
        bf16x8 a1 = *(const bf16x8*)(hb + 16 * HST + kk * 32);
#pragma unroll
        for (int g = 0; g < 4; ++g) {
          acc[g][0] = __builtin_amdgcn_mfma_f32_16x16x32_bf16(a0, bh[kk][g], acc[g][0], 0, 0, 0);
          acc[g][1] = __builtin_amdgcn_mfma_f32_16x16x32_bf16(a1, bh[kk][g], acc[g][1], 0, 0, 0);
        }
      }
    }

    // gates + state update + h store (i,f,g,o same-lane across acc[g])
    unsigned short* hdst = hbuf + (t & 1) * (BATCH * KH);
#pragma unroll
    for (int mt = 0; mt < 2; ++mt) {
#pragma unroll
      for (int r = 0; r < 4; ++r) {
        float zi = acc[0][mt][r] + bias[0];
        float zf = acc[1][mt][r] + bias[1];
        float zg = acc[2][mt][r] + bias[2];
        float zo = acc[3][mt][r] + bias[3];
        float gi = sigm(zi), gf = sigm(zf), go = sigm(zo), gg = tanhf_(zg);
        float c = gf * cst[mt][r] + gi * gg;
        cst[mt][r] = c;
        float h = go * tanhf_(c);
        if (uvalid) {
          int row = bg * BS + wm * 32 + mt * 16 + l4 * 4 + r;
          hdst[row * KH + j * HSL + u_local] = f2b(h);
        }
      }
      acc[0][mt] = {0.f, 0.f, 0.f, 0.f};
      acc[1][mt] = {0.f, 0.f, 0.f, 0.f};
      acc[2][mt] = {0.f, 0.f, 0.f, 0.f};
      acc[3][mt] = {0.f, 0.f, 0.f, 0.f};
    }

    __threadfence();
    __syncthreads();
    if (tid == 0)
      __hip_atomic_fetch_add(flags + t * GB + bg, 1, __ATOMIC_RELEASE, __HIP_MEMORY_SCOPE_AGENT);

    // write x(t+1) into the other LDS buffer (loads have landed by now)
    if (xact) {
      unsigned short* dst = &x_lds[(t + 1) & 1][xrow * XST + xf * 50];
#pragma unroll
      for (int e = 0; e < 25; ++e)
        *(unsigned*)(dst + 2 * e) = (unsigned)f2b(xv[e].x) | ((unsigned)f2b(xv[e].y) << 16);
    }

    // y(t-1) duty via MFMA (rotating slice; posted AFTER release -> off critical path)
    if (t > 0 && j == (t - 1) % GH) {
      const unsigned short* hb = h_lds + (w * 16 + l15) * HST + l4 * 8;
      f32x4 ay = {0.f, 0.f, 0.f, 0.f};
#pragma unroll
      for (int kk = 0; kk < 10; ++kk) {
        bf16x8 a = *(const bf16x8*)(hb + kk * 32);
        bf16x8 u = *(const bf16x8*)(Up + ((kk * 4 + l4) * 16 + l15) * 8);
        ay = __builtin_amdgcn_mfma_f32_16x16x32_bf16(a, u, ay, 0, 0, 0);
      }
      if (l15 < 5) {
#pragma unroll
        for (int q = 0; q < 4; ++q) {
          int row = bg * BS + w * 16 + l4 * 4 + q;
          out[(row * TT + (t - 1)) * 5 + l15] = ay[q] + b2v;
        }
      }
    }
  }

  // epilogue: y(119)
  if (j == (TT - 1) % GH) {
    if (tid == 0) {
      int* fp = flags + (TT - 1) * GB + bg;
      int it = 0;
      while (__hip_atomic_load(fp, __ATOMIC_ACQUIRE, __HIP_MEMORY_SCOPE_AGENT) < GH) {
        __builtin_amdgcn_s_sleep(2);
        if (++it > 100000) break;
      }
    }
    __syncthreads();
    const unsigned short* hsrc = hbuf + ((TT - 1) & 1) * (BATCH * KH) + bg * BS * KH;
#pragma unroll
    for (int p = 0; p < 10; ++p) {
      int g = tid + 256 * p;
      int row = g / 40, c = g - row * 40;
      *(int4*)(h_lds + row * HST + c * 8) = *(const int4*)(hsrc + g * 8);
    }
    __syncthreads();
    const unsigned short* hb = h_lds + (w * 16 + l15) * HST + l4 * 8;
    f32x4 ay = {0.f, 0.f, 0.f, 0.f};
#pragma unroll
    for (int kk = 0; kk < 10; ++kk) {
      bf16x8 a = *(const bf16x8*)(hb + kk * 32);
      bf16x8 u = *(const bf16x8*)(Up + ((kk * 4 + l4) * 16 + l15) * 8);
      ay = __builtin_amdgcn_mfma_f32_16x16x32_bf16(a, u, ay, 0, 0, 0);
    }
    if (l15 < 5) {
#pragma unroll
      for (int q = 0; q < 4; ++q) {
        int row = bg * BS + w * 16 + l4 * 4 + q;
        out[(row * TT + (TT - 1)) * 5 + l15] = ay[q] + b2v;
      }
    }
  }
}

extern "C" void kernel_launch(void* const* d_in, const int* in_sizes, int n_in,
                              void* d_out, int out_size, void* d_ws, size_t ws_size,
                              hipStream_t stream) {
  const int*   ids   = (const int*)d_in[0];
  const float* embed = (const float*)d_in[1];
  const float* Wx    = (const float*)d_in[2];
  const float* Wh    = (const float*)d_in[3];
  const float* b     = (const float*)d_in[4];
  const float* U     = (const float*)d_in[5];
  const float* b2    = (const float*)d_in[6];
  float* out = (float*)d_out;

  char* ws = (char*)d_ws;
  size_t off = 0;
  unsigned short* Wp   = (unsigned short*)(ws + off); off += (size_t)KH * NCOL * 2;      //   819,200
  unsigned short* Wxp  = (unsigned short*)(ws + off); off += (size_t)KX * NCOL * 2;      //   409,600
  float*          bp   = (float*)(ws + off);          off += (size_t)NCOL * 4;           //     5,120
  unsigned short* Up   = (unsigned short*)(ws + off); off += (size_t)KH * 16 * 2;        //    10,240
  unsigned short* hbuf = (unsigned short*)(ws + off); off += (size_t)2 * BATCH * KH * 2; // 1,310,720
  int*            flags= (int*)(ws + off);            off += (size_t)TT * GB * 4;        //     7,680
  if (ws_size < off) return;  // ~2.44 MB required

  hipMemsetAsync(flags, 0, TT * GB * 4, stream);
  k_reorder_w<<<(KH * NCOL + 255) / 256, 256, 0, stream>>>(Wh, Wp, HID, KH);
  k_reorder_w<<<(KX * NCOL + 255) / 256, 256, 0, stream>>>(Wx, Wxp, 150, KX);
  k_reorder_b<<<(NCOL + 255) / 256, 256, 0, stream>>>(b, bp);
  k_reorder_u<<<(KH * 16 + 255) / 256, 256, 0, stream>>>(U, Up);

  k_lstm<<<dim3(GB * GH), dim3(256), 0, stream>>>(ids, embed, Wp, Wxp, bp, Up,
                                                  hbuf, flags, b2, out);
}

// Round 3
// 1194.174 us; speedup vs baseline: 3.6881x; 3.6881x over previous
//
#include <hip/hip_runtime.h>

// LSTM: VOCAB=50000, EMBED=50, NFEAT=3, T=120, HIDDEN=300, NCLASS=5, BATCH=1024
// 160 blocks (16 batch-groups x 10 hidden-slices), 1 block/CU.
// Wh'/Wx' persist in VGPRs across all 120 steps. h exchanged via ping-pong
// global buffer through the COHERENT point (relaxed agent-scope atomics,
// sc0sc1 -> L3), no threadfence / no acquire-invalidate anywhere.

#define BATCH 1024
#define TT    120
#define HID   300
#define KX    160   // padded K for x (150 -> 160)
#define KH    320   // padded K for h (300 -> 320)
#define NCOL  1280  // padded gate columns: 10 slices * 128
#define GH    10    // hidden slices
#define GB    16    // batch groups
#define BS    64    // batch rows per group
#define HSL   30    // hidden units per slice
#define HST   328   // h_lds row stride in shorts (656B = 41*16B -> 2-way alias, free)
#define XST   168   // x_lds row stride in shorts (336B)

typedef __attribute__((ext_vector_type(8))) short bf16x8;
typedef __attribute__((ext_vector_type(4))) float f32x4;

__device__ __forceinline__ unsigned short f2b(float f) {
  union { float f; unsigned u; } v; v.f = f;
  unsigned r = v.u + 0x7fffu + ((v.u >> 16) & 1u);
  return (unsigned short)(r >> 16);
}
__device__ __forceinline__ float sigm(float x) {
  return __builtin_amdgcn_rcpf(1.f + __expf(-x));
}
__device__ __forceinline__ float tanhf_(float x) {
  return 2.f * __builtin_amdgcn_rcpf(1.f + __expf(-2.f * x)) - 1.f;
}

// W[k][g*300 + j*30 + u0] -> Wp[((k>>3)*NCOL + c)*8 + (k&7)], c = j*128+g*32+u0
__global__ void k_reorder_w(const float* __restrict__ W, unsigned short* __restrict__ Wp,
                            int krows, int kpad) {
  int tid = blockIdx.x * 256 + threadIdx.x;
  if (tid >= kpad * NCOL) return;
  int c = tid % NCOL, k = tid / NCOL;
  int j = c >> 7, r = c & 127, g = r >> 5, u0 = r & 31;
  float val = 0.f;
  if (k < krows && u0 < HSL) val = W[k * 1200 + g * 300 + j * HSL + u0];
  Wp[((k >> 3) * NCOL + c) * 8 + (k & 7)] = f2b(val);
}

__global__ void k_reorder_b(const float* __restrict__ b, float* __restrict__ bp) {
  int c = blockIdx.x * 256 + threadIdx.x;
  if (c >= NCOL) return;
  int j = c >> 7, r = c & 127, g = r >> 5, u0 = r & 31;
  bp[c] = (u0 < HSL) ? b[g * 300 + j * HSL + u0] : 0.f;
}

// U[k][n] (300x5) -> Up[((k>>3)*16 + n)*8 + (k&7)], n padded to 16, k to 320
__global__ void k_reorder_u(const float* __restrict__ U, unsigned short* __restrict__ Up) {
  int tid = blockIdx.x * 256 + threadIdx.x;
  if (tid >= KH * 16) return;
  int n = tid % 16, k = tid / 16;
  float v = (k < HID && n < 5) ? U[k * 5 + n] : 0.f;
  Up[((k >> 3) * 16 + n) * 8 + (k & 7)] = f2b(v);
}

__launch_bounds__(256, 1)
__global__ void k_lstm(const int* __restrict__ ids, const float* __restrict__ embed,
                       const unsigned short* __restrict__ Wp,
                       const unsigned short* __restrict__ Wxp,
                       const float* __restrict__ bp,
                       const unsigned short* __restrict__ Up,
                       unsigned short* __restrict__ hbuf,   // [2][1024][320] bf16
                       int* __restrict__ flags,             // [120][16]
                       const float* __restrict__ b2,
                       float* __restrict__ out) {
  __shared__ __align__(16) unsigned short h_lds[BS * HST];
  __shared__ __align__(16) unsigned short x_lds[2][BS * XST];

  const int tid = threadIdx.x;
  const int bid = blockIdx.x;
  const int bg = bid / GH, j = bid % GH;
  const int lane = tid & 63, w = tid >> 6;
  const int wm = w >> 1, wu = w & 1;   // 4 waves: 2 M-halves x 2 unit-halves
  const int l15 = lane & 15, l4 = lane >> 4;

  if (tid < BS) {
#pragma unroll
    for (int bq = 0; bq < 2; ++bq)
      for (int e = 150; e < XST; ++e) x_lds[bq][tid * XST + e] = 0;
  }

  const int colb = j * 128 + wu * 16 + l15;

  // persistent B fragments (linear k-pack: elem e of row (kk*4+l4) is k=kk*32+l4*8+e)
  bf16x8 bh[10][4], bx[5][4];
#pragma unroll
  for (int kk = 0; kk < 10; ++kk)
#pragma unroll
    for (int g = 0; g < 4; ++g)
      bh[kk][g] = *(const bf16x8*)(Wp + ((kk * 4 + l4) * NCOL + colb + g * 32) * 8);
#pragma unroll
  for (int kk = 0; kk < 5; ++kk)
#pragma unroll
    for (int g = 0; g < 4; ++g)
      bx[kk][g] = *(const bf16x8*)(Wxp + ((kk * 4 + l4) * NCOL + colb + g * 32) * 8);

  float bias[4];
#pragma unroll
  for (int g = 0; g < 4; ++g) bias[g] = bp[colb + g * 32];
  const float b2v = (l15 < 5) ? b2[l15] : 0.f;

  const int u_local = wu * 16 + l15;
  const bool pvalid = ((l15 & 1) == 0) && (u_local < HSL);  // even lane of a valid pair

  // gather x(0)
  if (tid < 192) {
    int xrow = tid / 3, xf = tid - 3 * xrow;
    int id = ids[((bg * BS + xrow) * TT + 0) * 3 + xf];
    const float* src = embed + (long)id * 50;
    unsigned short* dst = &x_lds[0][xrow * XST + xf * 50];
#pragma unroll
    for (int e = 0; e < 25; ++e) {
      float2 v = *(const float2*)(src + 2 * e);
      *(unsigned*)(dst + 2 * e) = (unsigned)f2b(v.x) | ((unsigned)f2b(v.y) << 16);
    }
  }
  __syncthreads();

  f32x4 acc[4][2];
  float cst[2][4];
#pragma unroll
  for (int g = 0; g < 4; ++g)
#pragma unroll
    for (int mt = 0; mt < 2; ++mt) acc[g][mt] = {0.f, 0.f, 0.f, 0.f};
#pragma unroll
  for (int mt = 0; mt < 2; ++mt)
#pragma unroll
    for (int r = 0; r < 4; ++r) cst[mt][r] = 0.f;

  for (int t = 0; t < TT; ++t) {
    if (t > 0) {
      if (tid == 0) {  // relaxed poll: coherent-point load, NO cache invalidates
        int* fp = flags + (t - 1) * GB + bg;
        int it = 0;
        while (__hip_atomic_load(fp, __ATOMIC_RELAXED, __HIP_MEMORY_SCOPE_AGENT) < GH) {
          __builtin_amdgcn_s_sleep(1);
          if (++it > 200000) break;  // bail -> wrong answer, not a hang
        }
      }
      __syncthreads();
      // stage h(t-1): coherent 8B loads (L3), then LDS
      const unsigned long long* hsrc8 = (const unsigned long long*)
          (hbuf + ((t - 1) & 1) * (BATCH * KH) + bg * BS * KH);
      unsigned long long vb[20];
#pragma unroll
      for (int p = 0; p < 20; ++p)
        vb[p] = __hip_atomic_load(hsrc8 + tid + 256 * p, __ATOMIC_RELAXED,
                                  __HIP_MEMORY_SCOPE_AGENT);
#pragma unroll
      for (int p = 0; p < 20; ++p) {
        int g = tid + 256 * p;          // 5120 chunks of 8B, 80 per row
        int row = g / 80, c = g - row * 80;
        *(unsigned long long*)(h_lds + row * HST + c * 4) = vb[p];
      }
      __syncthreads();
    }

    // issue x(t+1) gather loads early; pack after the MFMAs
    float2 xv[25];
    int xrow = 0, xf = 0;
    const bool xact = (t + 1 < TT) && (tid < 192);
    if (xact) {
      xrow = tid / 3; xf = tid - 3 * xrow;
      int id = ids[((bg * BS + xrow) * TT + (t + 1)) * 3 + xf];
      const float* src = embed + (long)id * 50;
#pragma unroll
      for (int e = 0; e < 25; ++e) xv[e] = *(const float2*)(src + 2 * e);
    }

    // GEMM1: x_t @ Wx'
    {
      const unsigned short* xb = &x_lds[t & 1][(wm * 32 + l15) * XST + l4 * 8];
#pragma unroll
      for (int kk = 0; kk < 5; ++kk) {
        bf16x8 a0 = *(const bf16x8*)(xb + kk * 32);
        bf16x8 a1 = *(const bf16x8*)(xb + 16 * XST + kk * 32);
#pragma unroll
        for (int g = 0; g < 4; ++g) {
          acc[g][0] = __builtin_amdgcn_mfma_f32_16x16x32_bf16(a0, bx[kk][g], acc[g][0], 0, 0, 0);
          acc[g][1] = __builtin_amdgcn_mfma_f32_16x16x32_bf16(a1, bx[kk][g], acc[g][1], 0, 0, 0);
        }
      }
    }
    // GEMM2: h(t-1) @ Wh'
    if (t > 0) {
      const unsigned short* hb = h_lds + (wm * 32 + l15) * HST + l4 * 8;
#pragma unroll
      for (int kk = 0; kk < 10; ++kk) {
        bf16x8 a0 = *(const bf16x8*)(hb + kk * 32);
        bf16x8 a1 = *(const bf16x8*)(hb + 16 * HST + kk * 32);
#pragma unroll
        for (int g = 0; g < 4; ++g) {
          acc[g][0] = __builtin_amdgcn_mfma_f32_16x16x32_bf16(a0, bh[kk][g], acc[g][0], 0, 0, 0);
          acc[g][1] = __builtin_amdgcn_mfma_f32_16x16x32_bf16(a1, bh[kk][g], acc[g][1], 0, 0, 0);
        }
      }
    }

    // gates + state update; h stored as paired-lane uint via coherent stores
    unsigned short* hdst = hbuf + (t & 1) * (BATCH * KH);
#pragma unroll
    for (int mt = 0; mt < 2; ++mt) {
#pragma unroll
      for (int r = 0; r < 4; ++r) {
        float zi = acc[0][mt][r] + bias[0];
        float zf = acc[1][mt][r] + bias[1];
        float zg = acc[2][mt][r] + bias[2];
        float zo = acc[3][mt][r] + bias[3];
        float gi = sigm(zi), gf = sigm(zf), go = sigm(zo), gg = tanhf_(zg);
        float c = gf * cst[mt][r] + gi * gg;
        cst[mt][r] = c;
        float h = go * tanhf_(c);
        unsigned hb16 = f2b(h);
        unsigned ob16 = (unsigned)__shfl_xor((int)hb16, 1);
        if (pvalid) {
          int row = bg * BS + wm * 32 + mt * 16 + l4 * 4 + r;
          unsigned* p = (unsigned*)(hdst + row * KH + j * HSL + u_local);
          __hip_atomic_store(p, hb16 | (ob16 << 16), __ATOMIC_RELAXED,
                             __HIP_MEMORY_SCOPE_AGENT);
        }
      }
      acc[0][mt] = {0.f, 0.f, 0.f, 0.f};
      acc[1][mt] = {0.f, 0.f, 0.f, 0.f};
      acc[2][mt] = {0.f, 0.f, 0.f, 0.f};
      acc[3][mt] = {0.f, 0.f, 0.f, 0.f};
    }

    // release: stores acked at coherence point, then one relaxed add
    asm volatile("s_waitcnt vmcnt(0)" ::: "memory");
    __syncthreads();
    if (tid == 0)
      __hip_atomic_fetch_add(flags + t * GB + bg, 1, __ATOMIC_RELAXED,
                             __HIP_MEMORY_SCOPE_AGENT);

    // write x(t+1) into the other LDS buffer (loads have landed by now)
    if (xact) {
      unsigned short* dst = &x_lds[(t + 1) & 1][xrow * XST + xf * 50];
#pragma unroll
      for (int e = 0; e < 25; ++e)
        *(unsigned*)(dst + 2 * e) = (unsigned)f2b(xv[e].x) | ((unsigned)f2b(xv[e].y) << 16);
    }

    // y(t-1) duty via MFMA (rotating slice; after release -> off critical path)
    if (t > 0 && j == (t - 1) % GH) {
      const unsigned short* hb = h_lds + (w * 16 + l15) * HST + l4 * 8;
      f32x4 ay = {0.f, 0.f, 0.f, 0.f};
#pragma unroll
      for (int kk = 0; kk < 10; ++kk) {
        bf16x8 a = *(const bf16x8*)(hb + kk * 32);
        bf16x8 u = *(const bf16x8*)(Up + ((kk * 4 + l4) * 16 + l15) * 8);
        ay = __builtin_amdgcn_mfma_f32_16x16x32_bf16(a, u, ay, 0, 0, 0);
      }
      if (l15 < 5) {
#pragma unroll
        for (int q = 0; q < 4; ++q) {
          int row = bg * BS + w * 16 + l4 * 4 + q;
          out[(row * TT + (t - 1)) * 5 + l15] = ay[q] + b2v;
        }
      }
    }
  }

  // epilogue: y(119)
  if (j == (TT - 1) % GH) {
    if (tid == 0) {
      int* fp = flags + (TT - 1) * GB + bg;
      int it = 0;
      while (__hip_atomic_load(fp, __ATOMIC_RELAXED, __HIP_MEMORY_SCOPE_AGENT) < GH) {
        __builtin_amdgcn_s_sleep(1);
        if (++it > 200000) break;
      }
    }
    __syncthreads();
    const unsigned long long* hsrc8 = (const unsigned long long*)
        (hbuf + ((TT - 1) & 1) * (BATCH * KH) + bg * BS * KH);
    unsigned long long vb[20];
#pragma unroll
    for (int p = 0; p < 20; ++p)
      vb[p] = __hip_atomic_load(hsrc8 + tid + 256 * p, __ATOMIC_RELAXED,
                                __HIP_MEMORY_SCOPE_AGENT);
#pragma unroll
    for (int p = 0; p < 20; ++p) {
      int g = tid + 256 * p;
      int row = g / 80, c = g - row * 80;
      *(unsigned long long*)(h_lds + row * HST + c * 4) = vb[p];
    }
    __syncthreads();
    const unsigned short* hb = h_lds + (w * 16 + l15) * HST + l4 * 8;
    f32x4 ay = {0.f, 0.f, 0.f, 0.f};
#pragma unroll
    for (int kk = 0; kk < 10; ++kk) {
      bf16x8 a = *(const bf16x8*)(hb + kk * 32);
      bf16x8 u = *(const bf16x8*)(Up + ((kk * 4 + l4) * 16 + l15) * 8);
      ay = __builtin_amdgcn_mfma_f32_16x16x32_bf16(a, u, ay, 0, 0, 0);
    }
    if (l15 < 5) {
#pragma unroll
      for (int q = 0; q < 4; ++q) {
        int row = bg * BS + w * 16 + l4 * 4 + q;
        out[(row * TT + (TT - 1)) * 5 + l15] = ay[q] + b2v;
      }
    }
  }
}

extern "C" void kernel_launch(void* const* d_in, const int* in_sizes, int n_in,
                              void* d_out, int out_size, void* d_ws, size_t ws_size,
                              hipStream_t stream) {
  const int*   ids   = (const int*)d_in[0];
  const float* embed = (const float*)d_in[1];
  const float* Wx    = (const float*)d_in[2];
  const float* Wh    = (const float*)d_in[3];
  const float* b     = (const float*)d_in[4];
  const float* U     = (const float*)d_in[5];
  const float* b2    = (const float*)d_in[6];
  float* out = (float*)d_out;

  char* ws = (char*)d_ws;
  size_t off = 0;
  unsigned short* Wp   = (unsigned short*)(ws + off); off += (size_t)KH * NCOL * 2;      //   819,200
  unsigned short* Wxp  = (unsigned short*)(ws + off); off += (size_t)KX * NCOL * 2;      //   409,600
  float*          bp   = (float*)(ws + off);          off += (size_t)NCOL * 4;           //     5,120
  unsigned short* Up   = (unsigned short*)(ws + off); off += (size_t)KH * 16 * 2;        //    10,240
  unsigned short* hbuf = (unsigned short*)(ws + off); off += (size_t)2 * BATCH * KH * 2; // 1,310,720
  int*            flags= (int*)(ws + off);            off += (size_t)TT * GB * 4;        //     7,680
  if (ws_size < off) return;  // ~2.44 MB required

  hipMemsetAsync(flags, 0, TT * GB * 4, stream);
  k_reorder_w<<<(KH * NCOL + 255) / 256, 256, 0, stream>>>(Wh, Wp, HID, KH);
  k_reorder_w<<<(KX * NCOL + 255) / 256, 256, 0, stream>>>(Wx, Wxp, 150, KX);
  k_reorder_b<<<(NCOL + 255) / 256, 256, 0, stream>>>(b, bp);
  k_reorder_u<<<(KH * 16 + 255) / 256, 256, 0, stream>>>(U, Up);

  k_lstm<<<dim3(GB * GH), dim3(256), 0, stream>>>(ids, embed, Wp, Wxp, bp, Up,
                                                  hbuf, flags, b2, out);
}

// Round 4
// 910.631 us; speedup vs baseline: 4.8365x; 1.3114x over previous
//
#include <hip/hip_runtime.h>

// LSTM: VOCAB=50000, EMBED=50, NFEAT=3, T=120, HIDDEN=300, NCLASS=5, BATCH=1024
// 160 blocks (16 batch-groups x 10 hidden-slices), 1 block/CU.
// Wh'/Wx'/U' persist in VGPRs. h exchange: sc0sc1 write-through stores ->
// relaxed flag poll -> ONE acquire (buffer_inv) -> plain cached dwordx4 loads
// directly into A-fragments (L2-shared across blocks on an XCD).

#define BATCH 1024
#define TT    120
#define HID   300
#define KX    160   // padded K for x (150 -> 160)
#define KH    320   // padded K for h (300 -> 320)
#define NCOL  1280  // padded gate columns: 10 slices * 128
#define GH    10    // hidden slices
#define GB    16    // batch groups
#define BS    64    // batch rows per group
#define HSL   30    // hidden units per slice
#define XST   168   // x_lds row stride in shorts (336B)
#define FSTR  32    // flag stride in ints (128B per flag -> no false sharing)

typedef __attribute__((ext_vector_type(8))) short bf16x8;
typedef __attribute__((ext_vector_type(4))) float f32x4;

__device__ __forceinline__ unsigned short f2b(float f) {
  union { float f; unsigned u; } v; v.f = f;
  unsigned r = v.u + 0x7fffu + ((v.u >> 16) & 1u);
  return (unsigned short)(r >> 16);
}
__device__ __forceinline__ float sigm(float x) {
  return __builtin_amdgcn_rcpf(1.f + __expf(-x));
}
__device__ __forceinline__ float tanhf_(float x) {
  return 2.f * __builtin_amdgcn_rcpf(1.f + __expf(-2.f * x)) - 1.f;
}

// W[k][g*300 + j*30 + u0] -> Wp[((k>>3)*NCOL + c)*8 + (k&7)], c = j*128+g*32+u0
__global__ void k_reorder_w(const float* __restrict__ W, unsigned short* __restrict__ Wp,
                            int krows, int kpad) {
  int tid = blockIdx.x * 256 + threadIdx.x;
  if (tid >= kpad * NCOL) return;
  int c = tid % NCOL, k = tid / NCOL;
  int j = c >> 7, r = c & 127, g = r >> 5, u0 = r & 31;
  float val = 0.f;
  if (k < krows && u0 < HSL) val = W[k * 1200 + g * 300 + j * HSL + u0];
  Wp[((k >> 3) * NCOL + c) * 8 + (k & 7)] = f2b(val);
}

__global__ void k_reorder_b(const float* __restrict__ b, float* __restrict__ bp) {
  int c = blockIdx.x * 256 + threadIdx.x;
  if (c >= NCOL) return;
  int j = c >> 7, r = c & 127, g = r >> 5, u0 = r & 31;
  bp[c] = (u0 < HSL) ? b[g * 300 + j * HSL + u0] : 0.f;
}

// U[k][n] (300x5) -> Up[((k>>3)*16 + n)*8 + (k&7)], n padded to 16, k to 320
__global__ void k_reorder_u(const float* __restrict__ U, unsigned short* __restrict__ Up) {
  int tid = blockIdx.x * 256 + threadIdx.x;
  if (tid >= KH * 16) return;
  int n = tid % 16, k = tid / 16;
  float v = (k < HID && n < 5) ? U[k * 5 + n] : 0.f;
  Up[((k >> 3) * 16 + n) * 8 + (k & 7)] = f2b(v);
}

__launch_bounds__(256, 1)
__global__ void k_lstm(const int* __restrict__ ids, const float* __restrict__ embed,
                       const unsigned short* __restrict__ Wp,
                       const unsigned short* __restrict__ Wxp,
                       const float* __restrict__ bp,
                       const unsigned short* __restrict__ Up,
                       unsigned short* __restrict__ hbuf,   // [2][1024][320] bf16
                       int* __restrict__ flags,             // [120][16] @ 128B stride
                       const float* __restrict__ b2,
                       float* __restrict__ out) {
  __shared__ __align__(16) unsigned short x_lds[2][BS * XST];

  const int tid = threadIdx.x;
  const int bid = blockIdx.x;
  const int bg = bid / GH, j = bid % GH;
  const int lane = tid & 63, w = tid >> 6;
  const int wm = w >> 1, wu = w & 1;   // 4 waves: 2 M-halves x 2 unit-halves
  const int l15 = lane & 15, l4 = lane >> 4;

  if (tid < BS) {
#pragma unroll
    for (int bq = 0; bq < 2; ++bq)
      for (int e = 150; e < XST; ++e) x_lds[bq][tid * XST + e] = 0;
  }

  const int colb = j * 128 + wu * 16 + l15;

  // persistent B fragments (linear k-pack: elem e of row (kk*4+l4) is k=kk*32+l4*8+e)
  bf16x8 bh[10][4], bx[5][4], up[10];
#pragma unroll
  for (int kk = 0; kk < 10; ++kk)
#pragma unroll
    for (int g = 0; g < 4; ++g)
      bh[kk][g] = *(const bf16x8*)(Wp + ((kk * 4 + l4) * NCOL + colb + g * 32) * 8);
#pragma unroll
  for (int kk = 0; kk < 5; ++kk)
#pragma unroll
    for (int g = 0; g < 4; ++g)
      bx[kk][g] = *(const bf16x8*)(Wxp + ((kk * 4 + l4) * NCOL + colb + g * 32) * 8);
#pragma unroll
  for (int kk = 0; kk < 10; ++kk)
    up[kk] = *(const bf16x8*)(Up + ((kk * 4 + l4) * 16 + l15) * 8);

  float bias[4];
#pragma unroll
  for (int g = 0; g < 4; ++g) bias[g] = bp[colb + g * 32];
  const float b2v = (l15 < 5) ? b2[l15] : 0.f;

  const int u_local = wu * 16 + l15;
  const bool pvalid = ((l15 & 1) == 0) && (u_local < HSL);

  // gather x(0)
  if (tid < 192) {
    int xrow = tid / 3, xf = tid - 3 * xrow;
    int id = ids[((bg * BS + xrow) * TT + 0) * 3 + xf];
    const float* src = embed + (long)id * 50;
    unsigned short* dst = &x_lds[0][xrow * XST + xf * 50];
#pragma unroll
    for (int e = 0; e < 25; ++e) {
      float2 v = *(const float2*)(src + 2 * e);
      *(unsigned*)(dst + 2 * e) = (unsigned)f2b(v.x) | ((unsigned)f2b(v.y) << 16);
    }
  }
  __syncthreads();

  f32x4 acc[4][2];
  float cst[2][4];
#pragma unroll
  for (int g = 0; g < 4; ++g)
#pragma unroll
    for (int mt = 0; mt < 2; ++mt) acc[g][mt] = {0.f, 0.f, 0.f, 0.f};
#pragma unroll
  for (int mt = 0; mt < 2; ++mt)
#pragma unroll
    for (int r = 0; r < 4; ++r) cst[mt][r] = 0.f;

  // GEMM1(0)
  {
    const unsigned short* xb = &x_lds[0][(wm * 32 + l15) * XST + l4 * 8];
#pragma unroll
    for (int kk = 0; kk < 5; ++kk) {
      bf16x8 a0 = *(const bf16x8*)(xb + kk * 32);
      bf16x8 a1 = *(const bf16x8*)(xb + 16 * XST + kk * 32);
#pragma unroll
      for (int g = 0; g < 4; ++g) {
        acc[g][0] = __builtin_amdgcn_mfma_f32_16x16x32_bf16(a0, bx[kk][g], acc[g][0], 0, 0, 0);
        acc[g][1] = __builtin_amdgcn_mfma_f32_16x16x32_bf16(a1, bx[kk][g], acc[g][1], 0, 0, 0);
      }
    }
  }

  for (int t = 0; t < TT; ++t) {
    if (t > 0) {
      if (tid == 0) {  // relaxed poll (no invalidates), then ONE acquire (inv)
        int* fp = flags + ((t - 1) * GB + bg) * FSTR;
        int it = 0;
        while (__hip_atomic_load(fp, __ATOMIC_RELAXED, __HIP_MEMORY_SCOPE_AGENT) < GH) {
          __builtin_amdgcn_s_sleep(1);
          if (++it > 200000) break;  // bail -> wrong answer, not a hang
        }
        (void)__hip_atomic_load(fp, __ATOMIC_ACQUIRE, __HIP_MEMORY_SCOPE_AGENT);
      }
      __syncthreads();

      // GEMM2: h(t-1) @ Wh', A-frags straight from global (cached, L2-shared)
      const unsigned short* hb = hbuf + ((t - 1) & 1) * (BATCH * KH) + (bg * BS) * KH;
      {
        const unsigned short* ar = hb + (wm * 32 + l15) * KH + l4 * 8;
#pragma unroll
        for (int kk = 0; kk < 10; ++kk) {
          bf16x8 a0 = *(const bf16x8*)(ar + kk * 32);
          bf16x8 a1 = *(const bf16x8*)(ar + 16 * KH + kk * 32);
#pragma unroll
          for (int g = 0; g < 4; ++g) {
            acc[g][0] = __builtin_amdgcn_mfma_f32_16x16x32_bf16(a0, bh[kk][g], acc[g][0], 0, 0, 0);
            acc[g][1] = __builtin_amdgcn_mfma_f32_16x16x32_bf16(a1, bh[kk][g], acc[g][1], 0, 0, 0);
          }
        }
      }
      // y(t-1) duty (before release: slot (t-1)&1 still protected; lines L1-hot)
      if (j == (t - 1) % GH) {
        const unsigned short* yb = hb + (w * 16 + l15) * KH + l4 * 8;
        f32x4 ay = {0.f, 0.f, 0.f, 0.f};
#pragma unroll
        for (int kk = 0; kk < 10; ++kk) {
          bf16x8 a = *(const bf16x8*)(yb + kk * 32);
          ay = __builtin_amdgcn_mfma_f32_16x16x32_bf16(a, up[kk], ay, 0, 0, 0);
        }
        if (l15 < 5) {
#pragma unroll
          for (int q = 0; q < 4; ++q) {
            int row = bg * BS + w * 16 + l4 * 4 + q;
            out[(row * TT + (t - 1)) * 5 + l15] = ay[q] + b2v;
          }
        }
      }
    }

    // issue x(t+1) gather loads (off critical path; land during gates)
    float2 xv[25];
    int xrow = 0, xf = 0;
    const bool xact = (t + 1 < TT) && (tid < 192);
    if (xact) {
      xrow = tid / 3; xf = tid - 3 * xrow;
      int id = ids[((bg * BS + xrow) * TT + (t + 1)) * 3 + xf];
      const float* src = embed + (long)id * 50;
#pragma unroll
      for (int e = 0; e < 25; ++e) xv[e] = *(const float2*)(src + 2 * e);
    }

    // gates + state update; h(t) stored pair-packed via write-through stores
    unsigned short* hdst = hbuf + (t & 1) * (BATCH * KH);
#pragma unroll
    for (int mt = 0; mt < 2; ++mt) {
#pragma unroll
      for (int r = 0; r < 4; ++r) {
        float zi = acc[0][mt][r] + bias[0];
        float zf = acc[1][mt][r] + bias[1];
        float zg = acc[2][mt][r] + bias[2];
        float zo = acc[3][mt][r] + bias[3];
        float gi = sigm(zi), gf = sigm(zf), go = sigm(zo), gg = tanhf_(zg);
        float c = gf * cst[mt][r] + gi * gg;
        cst[mt][r] = c;
        float h = go * tanhf_(c);
        unsigned hb16 = f2b(h);
        unsigned ob16 = (unsigned)__shfl_xor((int)hb16, 1);
        if (pvalid) {
          int row = bg * BS + wm * 32 + mt * 16 + l4 * 4 + r;
          unsigned* p = (unsigned*)(hdst + row * KH + j * HSL + u_local);
          __hip_atomic_store(p, hb16 | (ob16 << 16), __ATOMIC_RELAXED,
                             __HIP_MEMORY_SCOPE_AGENT);
        }
      }
      acc[0][mt] = {0.f, 0.f, 0.f, 0.f};
      acc[1][mt] = {0.f, 0.f, 0.f, 0.f};
      acc[2][mt] = {0.f, 0.f, 0.f, 0.f};
      acc[3][mt] = {0.f, 0.f, 0.f, 0.f};
    }

    // release
    asm volatile("s_waitcnt vmcnt(0)" ::: "memory");
    __syncthreads();
    if (tid == 0)
      __hip_atomic_fetch_add(flags + (t * GB + bg) * FSTR, 1, __ATOMIC_RELAXED,
                             __HIP_MEMORY_SCOPE_AGENT);

    // pack x(t+1)
    if (xact) {
      unsigned short* dst = &x_lds[(t + 1) & 1][xrow * XST + xf * 50];
#pragma unroll
      for (int e = 0; e < 25; ++e)
        *(unsigned*)(dst + 2 * e) = (unsigned)f2b(xv[e].x) | ((unsigned)f2b(xv[e].y) << 16);
    }
    __syncthreads();

    // GEMM1(t+1) — overlaps other blocks' waits
    if (t + 1 < TT) {
      const unsigned short* xb = &x_lds[(t + 1) & 1][(wm * 32 + l15) * XST + l4 * 8];
#pragma unroll
      for (int kk = 0; kk < 5; ++kk) {
        bf16x8 a0 = *(const bf16x8*)(xb + kk * 32);
        bf16x8 a1 = *(const bf16x8*)(xb + 16 * XST + kk * 32);
#pragma unroll
        for (int g = 0; g < 4; ++g) {
          acc[g][0] = __builtin_amdgcn_mfma_f32_16x16x32_bf16(a0, bx[kk][g], acc[g][0], 0, 0, 0);
          acc[g][1] = __builtin_amdgcn_mfma_f32_16x16x32_bf16(a1, bx[kk][g], acc[g][1], 0, 0, 0);
        }
      }
    }
  }

  // epilogue: y(119)
  if (j == (TT - 1) % GH) {
    if (tid == 0) {
      int* fp = flags + ((TT - 1) * GB + bg) * FSTR;
      int it = 0;
      while (__hip_atomic_load(fp, __ATOMIC_RELAXED, __HIP_MEMORY_SCOPE_AGENT) < GH) {
        __builtin_amdgcn_s_sleep(1);
        if (++it > 200000) break;
      }
      (void)__hip_atomic_load(fp, __ATOMIC_ACQUIRE, __HIP_MEMORY_SCOPE_AGENT);
    }
    __syncthreads();
    const unsigned short* hb = hbuf + ((TT - 1) & 1) * (BATCH * KH) + (bg * BS) * KH;
    const unsigned short* yb = hb + (w * 16 + l15) * KH + l4 * 8;
    f32x4 ay = {0.f, 0.f, 0.f, 0.f};
#pragma unroll
    for (int kk = 0; kk < 10; ++kk) {
      bf16x8 a = *(const bf16x8*)(yb + kk * 32);
      ay = __builtin_amdgcn_mfma_f32_16x16x32_bf16(a, up[kk], ay, 0, 0, 0);
    }
    if (l15 < 5) {
#pragma unroll
      for (int q = 0; q < 4; ++q) {
        int row = bg * BS + w * 16 + l4 * 4 + q;
        out[(row * TT + (TT - 1)) * 5 + l15] = ay[q] + b2v;
      }
    }
  }
}

extern "C" void kernel_launch(void* const* d_in, const int* in_sizes, int n_in,
                              void* d_out, int out_size, void* d_ws, size_t ws_size,
                              hipStream_t stream) {
  const int*   ids   = (const int*)d_in[0];
  const float* embed = (const float*)d_in[1];
  const float* Wx    = (const float*)d_in[2];
  const float* Wh    = (const float*)d_in[3];
  const float* b     = (const float*)d_in[4];
  const float* U     = (const float*)d_in[5];
  const float* b2    = (const float*)d_in[6];
  float* out = (float*)d_out;

  char* ws = (char*)d_ws;
  size_t off = 0;
  unsigned short* Wp   = (unsigned short*)(ws + off); off += (size_t)KH * NCOL * 2;       //   819,200
  unsigned short* Wxp  = (unsigned short*)(ws + off); off += (size_t)KX * NCOL * 2;       //   409,600
  float*          bp   = (float*)(ws + off);          off += (size_t)NCOL * 4;            //     5,120
  unsigned short* Up   = (unsigned short*)(ws + off); off += (size_t)KH * 16 * 2;         //    10,240
  unsigned short* hbuf = (unsigned short*)(ws + off); off += (size_t)2 * BATCH * KH * 2;  // 1,310,720
  int*            flags= (int*)(ws + off);            off += (size_t)TT * GB * FSTR * 4;  //   245,760
  if (ws_size < off) return;  // ~2.75 MB required

  hipMemsetAsync(flags, 0, TT * GB * FSTR * 4, stream);
  k_reorder_w<<<(KH * NCOL + 255) / 256, 256, 0, stream>>>(Wh, Wp, HID, KH);
  k_reorder_w<<<(KX * NCOL + 255) / 256, 256, 0, stream>>>(Wx, Wxp, 150, KX);
  k_reorder_b<<<(NCOL + 255) / 256, 256, 0, stream>>>(b, bp);
  k_reorder_u<<<(KH * 16 + 255) / 256, 256, 0, stream>>>(U, Up);

  k_lstm<<<dim3(GB * GH), dim3(256), 0, stream>>>(ids, embed, Wp, Wxp, bp, Up,
                                                  hbuf, flags, b2, out);
}

// Round 5
// 886.380 us; speedup vs baseline: 4.9688x; 1.0274x over previous
//
#include <hip/hip_runtime.h>

// LSTM: VOCAB=50000, EMBED=50, NFEAT=3, T=120, HIDDEN=300, NCLASS=5, BATCH=1024
// R5: GH=5 slices x GB=32 batch-groups (BS=32 rows) = 160 blocks, 1 block/CU.
// Traffic lever: h broadcast volume = GH * 614KB/step -> halved vs GH=10.
// Triple-buffered hbuf (slot=t%3) so y-duty runs AFTER flag release (off chain).
// h stored as 8B packed write-through atomics; read back cached after one
// acquire (inv) per step per block.

#define BATCH 1024
#define TT    120
#define HID   300
#define KX    160   // padded K for x (150 -> 160)
#define KH    320   // padded K for h: 5 slices * 64
#define SL    64    // padded units per slice
#define HSL   60    // valid units per slice
#define NCOL  1280  // 5 slices * 256 packed gate columns
#define GH    5     // hidden slices
#define GB    32    // batch groups
#define BS    32    // batch rows per group
#define XST   168   // x_lds row stride in shorts (336B)
#define FSTR  32    // flag stride in ints (128B)
#define NSLOT 3

typedef __attribute__((ext_vector_type(8))) short bf16x8;
typedef __attribute__((ext_vector_type(4))) float f32x4;

__device__ __forceinline__ unsigned short f2b(float f) {
  union { float f; unsigned u; } v; v.f = f;
  unsigned r = v.u + 0x7fffu + ((v.u >> 16) & 1u);
  return (unsigned short)(r >> 16);
}
__device__ __forceinline__ float sigm(float x) {
  return __builtin_amdgcn_rcpf(1.f + __expf(-x));
}
__device__ __forceinline__ float tanhf_(float x) {
  return 2.f * __builtin_amdgcn_rcpf(1.f + __expf(-2.f * x)) - 1.f;
}

// column map: c in [0,1280): j=c>>8, r=c&255, g=r>>6, u0=r&63; valid u0<60
// logical col = g*300 + j*60 + u0
// Wh k map (matches hbuf layout): k in [0,320): js=k>>6, v0=k&63; valid v0<60
__global__ void k_reorder_wh(const float* __restrict__ W, unsigned short* __restrict__ Wp) {
  int tid = blockIdx.x * 256 + threadIdx.x;
  if (tid >= KH * NCOL) return;
  int c = tid % NCOL, k = tid / NCOL;
  int js = k >> 6, v0 = k & 63;
  int j = c >> 8, r = c & 255, g = r >> 6, u0 = r & 63;
  float val = 0.f;
  if (v0 < HSL && u0 < HSL) val = W[(js * HSL + v0) * 1200 + g * 300 + j * HSL + u0];
  Wp[((k >> 3) * NCOL + c) * 8 + (k & 7)] = f2b(val);
}

__global__ void k_reorder_wx(const float* __restrict__ W, unsigned short* __restrict__ Wp) {
  int tid = blockIdx.x * 256 + threadIdx.x;
  if (tid >= KX * NCOL) return;
  int c = tid % NCOL, k = tid / NCOL;
  int j = c >> 8, r = c & 255, g = r >> 6, u0 = r & 63;
  float val = 0.f;
  if (k < 150 && u0 < HSL) val = W[k * 1200 + g * 300 + j * HSL + u0];
  Wp[((k >> 3) * NCOL + c) * 8 + (k & 7)] = f2b(val);
}

__global__ void k_reorder_b(const float* __restrict__ b, float* __restrict__ bp) {
  int c = blockIdx.x * 256 + threadIdx.x;
  if (c >= NCOL) return;
  int j = c >> 8, r = c & 255, g = r >> 6, u0 = r & 63;
  bp[c] = (u0 < HSL) ? b[g * 300 + j * HSL + u0] : 0.f;
}

// U'[k_pad][n16], k_pad slice-padded like hbuf
__global__ void k_reorder_u(const float* __restrict__ U, unsigned short* __restrict__ Up) {
  int tid = blockIdx.x * 256 + threadIdx.x;
  if (tid >= KH * 16) return;
  int n = tid % 16, k = tid / 16;
  int js = k >> 6, v0 = k & 63;
  float v = (v0 < HSL && n < 5) ? U[(js * HSL + v0) * 5 + n] : 0.f;
  Up[((k >> 3) * 16 + n) * 8 + (k & 7)] = f2b(v);
}

__launch_bounds__(256, 1)
__global__ void k_lstm(const int* __restrict__ ids, const float* __restrict__ embed,
                       const unsigned short* __restrict__ Wp,
                       const unsigned short* __restrict__ Wxp,
                       const float* __restrict__ bp,
                       const unsigned short* __restrict__ Up,
                       unsigned short* __restrict__ hbuf,   // [3][1024][320] bf16
                       int* __restrict__ flags,             // [120][32] @128B
                       const float* __restrict__ b2,
                       float* __restrict__ out) {
  __shared__ __align__(16) unsigned short x_lds[2][BS * XST];

  const int tid = threadIdx.x;
  const int bid = blockIdx.x;
  const int bg = bid / GH, j = bid % GH;
  const int lane = tid & 63, w = tid >> 6;      // 4 waves; wave w owns units w*16..w*16+15
  const int l15 = lane & 15, l4 = lane >> 4;

  if (tid < BS) {
#pragma unroll
    for (int bq = 0; bq < 2; ++bq)
      for (int e = 150; e < XST; ++e) x_lds[bq][tid * XST + e] = 0;
  }

  const int colb = j * 256 + w * 16 + l15;

  // persistent B fragments (linear k-pack: elem e of k-row (kk*4+l4) is k=kk*32+l4*8+e)
  bf16x8 bh[10][4], bx[5][4], up[10];
#pragma unroll
  for (int kk = 0; kk < 10; ++kk)
#pragma unroll
    for (int g = 0; g < 4; ++g)
      bh[kk][g] = *(const bf16x8*)(Wp + ((kk * 4 + l4) * NCOL + colb + g * 64) * 8);
#pragma unroll
  for (int kk = 0; kk < 5; ++kk)
#pragma unroll
    for (int g = 0; g < 4; ++g)
      bx[kk][g] = *(const bf16x8*)(Wxp + ((kk * 4 + l4) * NCOL + colb + g * 64) * 8);
#pragma unroll
  for (int kk = 0; kk < 10; ++kk)
    up[kk] = *(const bf16x8*)(Up + ((kk * 4 + l4) * 16 + l15) * 8);

  float bias[4];
#pragma unroll
  for (int g = 0; g < 4; ++g) bias[g] = bp[colb + g * 64];
  const float b2v = (l15 < 5) ? b2[l15] : 0.f;

  // ---- x(0) gather: 192 threads = 32 rows x 3 feats x 2 halves (26/24 split)
  {
    if (tid < 192) {
      int xrow = tid / 6, half = tid % 6, f = half >> 1, hh = half & 1;
      int nf2 = hh ? 12 : 13;
      int koff = f * 50 + (hh ? 26 : 0);
      int id = ids[((bg * BS + xrow) * TT + 0) * 3 + f];
      const float* src = embed + (long)id * 50 + (hh ? 26 : 0);
      unsigned short* dst = &x_lds[0][xrow * XST + koff];
#pragma unroll
      for (int e = 0; e < 13; ++e)
        if (e < nf2) {
          float2 v = *(const float2*)(src + 2 * e);
          *(unsigned*)(dst + 2 * e) = (unsigned)f2b(v.x) | ((unsigned)f2b(v.y) << 16);
        }
    }
  }
  __syncthreads();

  f32x4 acc[4][2];
  float cst[2][4];
#pragma unroll
  for (int g = 0; g < 4; ++g)
#pragma unroll
    for (int mt = 0; mt < 2; ++mt) acc[g][mt] = {0.f, 0.f, 0.f, 0.f};
#pragma unroll
  for (int mt = 0; mt < 2; ++mt)
#pragma unroll
    for (int r = 0; r < 4; ++r) cst[mt][r] = 0.f;

  // GEMM1(0)
  {
    const unsigned short* xb = &x_lds[0][l15 * XST + l4 * 8];
#pragma unroll
    for (int kk = 0; kk < 5; ++kk) {
      bf16x8 a0 = *(const bf16x8*)(xb + kk * 32);
      bf16x8 a1 = *(const bf16x8*)(xb + 16 * XST + kk * 32);
#pragma unroll
      for (int g = 0; g < 4; ++g) {
        acc[g][0] = __builtin_amdgcn_mfma_f32_16x16x32_bf16(a0, bx[kk][g], acc[g][0], 0, 0, 0);
        acc[g][1] = __builtin_amdgcn_mfma_f32_16x16x32_bf16(a1, bx[kk][g], acc[g][1], 0, 0, 0);
      }
    }
  }

  for (int t = 0; t < TT; ++t) {
    // issue x(t+1) loads first — independent of flags, latency hides under wait
    float2 xv[13];
    int xrow = 0, koff = 0, nf2 = 0;
    const bool xact = (t + 1 < TT) && (tid < 192);
    if (xact) {
      xrow = tid / 6; int half = tid % 6, f = half >> 1, hh = half & 1;
      nf2 = hh ? 12 : 13;
      koff = f * 50 + (hh ? 26 : 0);
      int id = ids[((bg * BS + xrow) * TT + (t + 1)) * 3 + f];
      const float* src = embed + (long)id * 50 + (hh ? 26 : 0);
#pragma unroll
      for (int e = 0; e < 13; ++e)
        if (e < nf2) xv[e] = *(const float2*)(src + 2 * e);
    }

    if (t > 0) {
      if (tid == 0) {  // relaxed poll, then ONE acquire (inv)
        int* fp = flags + ((t - 1) * GB + bg) * FSTR;
        int it = 0;
        while (__hip_atomic_load(fp, __ATOMIC_RELAXED, __HIP_MEMORY_SCOPE_AGENT) < GH) {
          __builtin_amdgcn_s_sleep(1);
          if (++it > 200000) break;  // bail -> wrong answer, not a hang
        }
        (void)__hip_atomic_load(fp, __ATOMIC_ACQUIRE, __HIP_MEMORY_SCOPE_AGENT);
      }
      __syncthreads();

      // GEMM2: h(t-1) @ Wh', A-frags via cached loads (all 4 waves share rows via L1)
      const unsigned short* ar =
          hbuf + ((t - 1) % NSLOT) * (BATCH * KH) + (bg * BS + l15) * KH + l4 * 8;
#pragma unroll
      for (int kk = 0; kk < 10; ++kk) {
        bf16x8 a0 = *(const bf16x8*)(ar + kk * 32);
        bf16x8 a1 = *(const bf16x8*)(ar + 16 * KH + kk * 32);
#pragma unroll
        for (int g = 0; g < 4; ++g) {
          acc[g][0] = __builtin_amdgcn_mfma_f32_16x16x32_bf16(a0, bh[kk][g], acc[g][0], 0, 0, 0);
          acc[g][1] = __builtin_amdgcn_mfma_f32_16x16x32_bf16(a1, bh[kk][g], acc[g][1], 0, 0, 0);
        }
      }
    }

    // gates + state update; h(t) packed 4-wide via shfl tree -> 8B sc-stores
    unsigned short* hdst = hbuf + (t % NSLOT) * (BATCH * KH);
#pragma unroll
    for (int mt = 0; mt < 2; ++mt) {
#pragma unroll
      for (int r = 0; r < 4; ++r) {
        float zi = acc[0][mt][r] + bias[0];
        float zf = acc[1][mt][r] + bias[1];
        float zg = acc[2][mt][r] + bias[2];
        float zo = acc[3][mt][r] + bias[3];
        float gi = sigm(zi), gf = sigm(zf), go = sigm(zo), gg = tanhf_(zg);
        float c = gf * cst[mt][r] + gi * gg;
        cst[mt][r] = c;
        float h = go * tanhf_(c);
        unsigned v = f2b(h);
        unsigned p1 = v | ((unsigned)__shfl_xor((int)v, 1) << 16);
        unsigned long long p2 = (unsigned long long)p1 |
            ((unsigned long long)(unsigned)__shfl_xor((int)p1, 2) << 32);
        if ((l15 & 3) == 0) {
          int row = bg * BS + mt * 16 + l4 * 4 + r;
          __hip_atomic_store((unsigned long long*)(hdst + row * KH + j * SL + w * 16 + l15),
                             p2, __ATOMIC_RELAXED, __HIP_MEMORY_SCOPE_AGENT);
        }
      }
      acc[0][mt] = {0.f, 0.f, 0.f, 0.f};
      acc[1][mt] = {0.f, 0.f, 0.f, 0.f};
      acc[2][mt] = {0.f, 0.f, 0.f, 0.f};
      acc[3][mt] = {0.f, 0.f, 0.f, 0.f};
    }

    // release
    asm volatile("s_waitcnt vmcnt(0)" ::: "memory");
    __syncthreads();
    if (tid == 0)
      __hip_atomic_fetch_add(flags + (t * GB + bg) * FSTR, 1, __ATOMIC_RELAXED,
                             __HIP_MEMORY_SCOPE_AGENT);

    // y(t-1) duty — AFTER release (triple buffer makes this WAR-safe), L1-hot lines
    if (t > 0 && j == (t - 1) % GH && w < 2) {
      const unsigned short* yb =
          hbuf + ((t - 1) % NSLOT) * (BATCH * KH) + (bg * BS + w * 16 + l15) * KH + l4 * 8;
      f32x4 ay = {0.f, 0.f, 0.f, 0.f};
#pragma unroll
      for (int kk = 0; kk < 10; ++kk) {
        bf16x8 a = *(const bf16x8*)(yb + kk * 32);
        ay = __builtin_amdgcn_mfma_f32_16x16x32_bf16(a, up[kk], ay, 0, 0, 0);
      }
      if (l15 < 5) {
#pragma unroll
        for (int q = 0; q < 4; ++q) {
          int row = bg * BS + w * 16 + l4 * 4 + q;
          out[(row * TT + (t - 1)) * 5 + l15] = ay[q] + b2v;
        }
      }
    }

    // pack x(t+1)
    if (xact) {
      unsigned short* dst = &x_lds[(t + 1) & 1][xrow * XST + koff];
#pragma unroll
      for (int e = 0; e < 13; ++e)
        if (e < nf2)
          *(unsigned*)(dst + 2 * e) = (unsigned)f2b(xv[e].x) | ((unsigned)f2b(xv[e].y) << 16);
    }
    __syncthreads();

    // GEMM1(t+1) — overlaps other blocks' progress
    if (t + 1 < TT) {
      const unsigned short* xb = &x_lds[(t + 1) & 1][l15 * XST + l4 * 8];
#pragma unroll
      for (int kk = 0; kk < 5; ++kk) {
        bf16x8 a0 = *(const bf16x8*)(xb + kk * 32);
        bf16x8 a1 = *(const bf16x8*)(xb + 16 * XST + kk * 32);
#pragma unroll
        for (int g = 0; g < 4; ++g) {
          acc[g][0] = __builtin_amdgcn_mfma_f32_16x16x32_bf16(a0, bx[kk][g], acc[g][0], 0, 0, 0);
          acc[g][1] = __builtin_amdgcn_mfma_f32_16x16x32_bf16(a1, bx[kk][g], acc[g][1], 0, 0, 0);
        }
      }
    }
  }

  // epilogue: y(119)
  if (j == (TT - 1) % GH) {
    if (tid == 0) {
      int* fp = flags + ((TT - 1) * GB + bg) * FSTR;
      int it = 0;
      while (__hip_atomic_load(fp, __ATOMIC_RELAXED, __HIP_MEMORY_SCOPE_AGENT) < GH) {
        __builtin_amdgcn_s_sleep(1);
        if (++it > 200000) break;
      }
      (void)__hip_atomic_load(fp, __ATOMIC_ACQUIRE, __HIP_MEMORY_SCOPE_AGENT);
    }
    __syncthreads();
    if (w < 2) {
      const unsigned short* yb =
          hbuf + ((TT - 1) % NSLOT) * (BATCH * KH) + (bg * BS + w * 16 + l15) * KH + l4 * 8;
      f32x4 ay = {0.f, 0.f, 0.f, 0.f};
#pragma unroll
      for (int kk = 0; kk < 10; ++kk) {
        bf16x8 a = *(const bf16x8*)(yb + kk * 32);
        ay = __builtin_amdgcn_mfma_f32_16x16x32_bf16(a, up[kk], ay, 0, 0, 0);
      }
      if (l15 < 5) {
#pragma unroll
        for (int q = 0; q < 4; ++q) {
          int row = bg * BS + w * 16 + l4 * 4 + q;
          out[(row * TT + (TT - 1)) * 5 + l15] = ay[q] + b2v;
        }
      }
    }
  }
}

extern "C" void kernel_launch(void* const* d_in, const int* in_sizes, int n_in,
                              void* d_out, int out_size, void* d_ws, size_t ws_size,
                              hipStream_t stream) {
  const int*   ids   = (const int*)d_in[0];
  const float* embed = (const float*)d_in[1];
  const float* Wx    = (const float*)d_in[2];
  const float* Wh    = (const float*)d_in[3];
  const float* b     = (const float*)d_in[4];
  const float* U     = (const float*)d_in[5];
  const float* b2    = (const float*)d_in[6];
  float* out = (float*)d_out;

  char* ws = (char*)d_ws;
  size_t off = 0;
  unsigned short* Wp   = (unsigned short*)(ws + off); off += (size_t)KH * NCOL * 2;          //   819,200
  unsigned short* Wxp  = (unsigned short*)(ws + off); off += (size_t)KX * NCOL * 2;          //   409,600
  float*          bp   = (float*)(ws + off);          off += (size_t)NCOL * 4;               //     5,120
  unsigned short* Up   = (unsigned short*)(ws + off); off += (size_t)KH * 16 * 2;            //    10,240
  unsigned short* hbuf = (unsigned short*)(ws + off); off += (size_t)NSLOT * BATCH * KH * 2; // 1,966,080
  int*            flags= (int*)(ws + off);            off += (size_t)TT * GB * FSTR * 4;     //   491,520
  if (ws_size < off) return;  // ~3.7 MB required

  hipMemsetAsync(flags, 0, TT * GB * FSTR * 4, stream);
  k_reorder_wh<<<(KH * NCOL + 255) / 256, 256, 0, stream>>>(Wh, Wp);
  k_reorder_wx<<<(KX * NCOL + 255) / 256, 256, 0, stream>>>(Wx, Wxp);
  k_reorder_b<<<(NCOL + 255) / 256, 256, 0, stream>>>(b, bp);
  k_reorder_u<<<(KH * 16 + 255) / 256, 256, 0, stream>>>(U, Up);

  k_lstm<<<dim3(GB * GH), dim3(256), 0, stream>>>(ids, embed, Wp, Wxp, bp, Up,
                                                  hbuf, flags, b2, out);
}